// Round 4
// baseline (167.341 us; speedup 1.0000x reference)
//
#include <hip/hip_runtime.h>

#define D_  256
#define H1_ 256
#define H2_ 128
#define B_  2
#define LQ_ 512
#define LK_ 512
#define BK  64

typedef float  f32x4  __attribute__((ext_vector_type(4)));
typedef __bf16 bf16x8 __attribute__((ext_vector_type(8)));
typedef __bf16 bf16x4 __attribute__((ext_vector_type(4)));

// ---- prep: qp = query@W1[:D] + b1 ; kp = key@W1[D:] ; w2t = bf16(W2^T) ----
// (unchanged from R3 — passing)
__global__ __launch_bounds__(512) void prep_kernel(
    const float* __restrict__ query, const float* __restrict__ key,
    const float* __restrict__ W1, const float* __restrict__ b1,
    const float* __restrict__ W2,
    float* __restrict__ qp, float* __restrict__ kp, __bf16* __restrict__ w2t) {
  const int blk = blockIdx.x;
  const int tid = threadIdx.x;
  if (blk >= 256) {
    const int id = (blk - 256) * 512 + tid;
    const int n = id >> 8;
    const int k = id & 255;
    w2t[n * H1_ + k] = (__bf16)W2[k * H2_ + n];
    return;
  }
  __shared__ float in_lds[8][D_];
  __shared__ float part[8][H1_];
  const int row0 = blk * 8;
  const int sel  = row0 >> 10;
  const float* __restrict__ src = sel ? key : query;
  const int base = (row0 & 1023) * D_;
  for (int i = tid; i < 8 * D_; i += 512)
    in_lds[i >> 8][i & 255] = src[base + i];
  __syncthreads();
  const int h  = tid & 255;
  const int kh = tid >> 8;
  float acc[8] = {0.f, 0.f, 0.f, 0.f, 0.f, 0.f, 0.f, 0.f};
  const float* __restrict__ w = W1 + sel * D_ * H1_ + kh * 128 * H1_ + h;
#pragma unroll 4
  for (int dd = 0; dd < 128; ++dd) {
    const float wv = w[dd * H1_];
    const int d = kh * 128 + dd;
#pragma unroll
    for (int r = 0; r < 8; ++r) acc[r] += in_lds[r][d] * wv;
  }
  if (kh == 1) {
#pragma unroll
    for (int r = 0; r < 8; ++r) part[r][h] = acc[r];
  }
  __syncthreads();
  if (kh == 0) {
    const float bias = sel ? 0.0f : b1[h];
    float* __restrict__ dst = sel ? kp : qp;
#pragma unroll
    for (int r = 0; r < 8; ++r)
      dst[base + r * H1_ + h] = acc[r] + part[r][h] + bias;
  }
}

// ---- score kernel v3: XOR-swizzled LDS (no pad), 4 blocks/CU ----
// LDS layout: element k of row r lives at r*BK + ((k>>3) ^ (r&7))*8 + (k&7).
// 16-B chunks stay 16-B aligned (b128/b64 ops intact); MFMA b128 reads land
// evenly on all bank groups (8-cycle minimum, no conflict overhead).
__global__ __launch_bounds__(256, 4) void score_kernel(
    const float* __restrict__ qp, const float* __restrict__ kp,
    const __bf16* __restrict__ w2t,
    const float* __restrict__ b2, const float* __restrict__ W3,
    const float* __restrict__ b3, float* __restrict__ scores) {
  __shared__ __align__(16) __bf16 A_lds[128 * BK];   // 16 KB
  __shared__ __align__(16) __bf16 B_lds[128 * BK];   // 16 KB
  __shared__ float  spart[2][128];                   // 1 KB

  const int b  = blockIdx.z;
  const int q0 = blockIdx.y * 8;
  const int k0 = blockIdx.x * 16;
  const int tid  = threadIdx.x;
  const int wave = tid >> 6;
  const int lane = tid & 63;
  const int quad = lane >> 4;
  const int l16  = lane & 15;
  const int wm   = wave >> 1;
  const int wn   = wave & 1;
  const int h8   = l16 & 7;          // row&7 for this lane's fragment rows

  const float* __restrict__ qpb = qp + (b * LQ_ + q0) * H1_;
  const float* __restrict__ kpb = kp + (b * LK_ + k0) * H1_;

  f32x4 acc[4][4];
#pragma unroll
  for (int mt = 0; mt < 4; ++mt)
#pragma unroll
    for (int nt = 0; nt < 4; ++nt)
      acc[mt][nt] = (f32x4){0.f, 0.f, 0.f, 0.f};

  for (int kc = 0; kc < H1_ / BK; ++kc) {
    // --- A tile: A[r][k] = relu(qp[qi][k] + kp[ki][k]), swizzled store ---
#pragma unroll
    for (int i = 0; i < 8; ++i) {
      const int r  = i * 16 + (tid >> 4);
      const int kg = tid & 15;               // b64 piece: k = kg*4..kg*4+3
      const int qi = r >> 4, ki = r & 15;
      const int kcol = kc * BK + kg * 4;
      const float4 qv = *(const float4*)(qpb + qi * H1_ + kcol);
      const float4 kv = *(const float4*)(kpb + ki * H1_ + kcol);
      bf16x4 a;
      a[0] = (__bf16)fmaxf(qv.x + kv.x, 0.f);
      a[1] = (__bf16)fmaxf(qv.y + kv.y, 0.f);
      a[2] = (__bf16)fmaxf(qv.z + kv.z, 0.f);
      a[3] = (__bf16)fmaxf(qv.w + kv.w, 0.f);
      const int sw = (((kg >> 1) ^ (r & 7)) << 3) + ((kg & 1) << 2);
      *(bf16x4*)(&A_lds[r * BK + sw]) = a;
    }
    // --- B tile: 1024 16-B chunks, swizzled ---
#pragma unroll
    for (int i = 0; i < 4; ++i) {
      const int u = i * 256 + tid;
      const int n = u >> 3, c = u & 7;
      *(uint4*)(&B_lds[n * BK + (((c ^ (n & 7)) << 3))]) =
          *(const uint4*)(w2t + n * H1_ + kc * BK + c * 8);
    }
    __syncthreads();
#pragma unroll
    for (int ks = 0; ks < BK / 32; ++ks) {
      const int cbase = ks * 4 + quad;       // chunk index 0..7
      bf16x8 af[4], bfr[4];
#pragma unroll
      for (int mt = 0; mt < 4; ++mt) {
        const int ra = wm * 64 + mt * 16 + l16;
        af[mt] = *(const bf16x8*)(&A_lds[ra * BK + ((cbase ^ h8) << 3)]);
      }
#pragma unroll
      for (int nt = 0; nt < 4; ++nt) {
        const int rb = wn * 64 + nt * 16 + l16;
        bfr[nt] = *(const bf16x8*)(&B_lds[rb * BK + ((cbase ^ h8) << 3)]);
      }
#pragma unroll
      for (int mt = 0; mt < 4; ++mt)
#pragma unroll
        for (int nt = 0; nt < 4; ++nt)
          acc[mt][nt] = __builtin_amdgcn_mfma_f32_16x16x32_bf16(
              af[mt], bfr[nt], acc[mt][nt], 0, 0, 0);
    }
    __syncthreads();
  }

  // --- epilogue: score = sum_n relu(h2 + b2[n]) * W3[n] + b3 ---
  float part[4][4];
#pragma unroll
  for (int mt = 0; mt < 4; ++mt)
#pragma unroll
    for (int rg = 0; rg < 4; ++rg) part[mt][rg] = 0.f;
#pragma unroll
  for (int nt = 0; nt < 4; ++nt) {
    const int col = wn * 64 + nt * 16 + l16;
    const float b2v = b2[col];
    const float w3v = W3[col];
#pragma unroll
    for (int mt = 0; mt < 4; ++mt)
#pragma unroll
      for (int rg = 0; rg < 4; ++rg) {
        float h2 = acc[mt][nt][rg] + b2v;
        h2 = fmaxf(h2, 0.f);
        part[mt][rg] += h2 * w3v;
      }
  }
#pragma unroll
  for (int off = 1; off < 16; off <<= 1)
#pragma unroll
    for (int mt = 0; mt < 4; ++mt)
#pragma unroll
      for (int rg = 0; rg < 4; ++rg)
        part[mt][rg] += __shfl_xor(part[mt][rg], off, 64);
  if (l16 == 0) {
#pragma unroll
    for (int mt = 0; mt < 4; ++mt)
#pragma unroll
      for (int rg = 0; rg < 4; ++rg) {
        const int rl = wm * 64 + mt * 16 + quad * 4 + rg;
        spart[wn][rl] = part[mt][rg];
      }
  }
  __syncthreads();
  if (tid < 128) {
    const float s = spart[0][tid] + spart[1][tid] + b3[0];
    const int qi = tid >> 4, ki = tid & 15;
    scores[(b * LQ_ + q0 + qi) * LK_ + k0 + ki] = s;
  }
}

// ---- fused softmax + out: one block per (b, 8 q-rows) ----
// Block exclusively owns its 8 attn rows -> in-place score->prob rewrite is
// race-free. Phase 1: wave w softmaxes row w (shuffle reduce). Phase 2: the
// proven out loop (kh-split-2, 8 q-accumulators, LDS combine).
__global__ __launch_bounds__(512) void smout_kernel(
    float* __restrict__ attn, const int* __restrict__ mask,
    const float* __restrict__ value, float* __restrict__ out) {
  const int qg = blockIdx.x, b = blockIdx.y;
  const int tid = threadIdx.x;
  __shared__ float a_lds[8][LK_];   // 16 KB probs
  __shared__ float p_lds[8][D_];    // 8 KB partials (kh=1)
  const int row0 = b * LQ_ + qg * 8;
  const int w = tid >> 6, lane = tid & 63;
  float* __restrict__ srow = attn + (row0 + w) * LK_;
  const int* __restrict__ mrow = mask + (row0 + w) * LK_;
  float v[8];
#pragma unroll
  for (int j = 0; j < 8; ++j) {
    float s = srow[lane + j * 64];
    if (mrow[lane + j * 64] == 0) s = -1e9f;
    v[j] = s;
  }
  float m = v[0];
#pragma unroll
  for (int j = 1; j < 8; ++j) m = fmaxf(m, v[j]);
#pragma unroll
  for (int off = 32; off; off >>= 1) m = fmaxf(m, __shfl_xor(m, off, 64));
  float sum = 0.f;
#pragma unroll
  for (int j = 0; j < 8; ++j) { v[j] = __expf(v[j] - m); sum += v[j]; }
#pragma unroll
  for (int off = 32; off; off >>= 1) sum += __shfl_xor(sum, off, 64);
  const float inv = 1.f / sum;
#pragma unroll
  for (int j = 0; j < 8; ++j) {
    const float p = v[j] * inv;
    a_lds[w][lane + j * 64] = p;
    srow[lane + j * 64] = p;
  }
  __syncthreads();
  const int d = tid & 255, kh = tid >> 8;
  float acc[8] = {0.f, 0.f, 0.f, 0.f, 0.f, 0.f, 0.f, 0.f};
  const float* __restrict__ vb = value + (b * LK_ + kh * 256) * D_ + d;
#pragma unroll 4
  for (int k = 0; k < 256; ++k) {
    const float vv = vb[k * D_];
    const float* __restrict__ ar = &a_lds[0][kh * 256 + k];
#pragma unroll
    for (int q = 0; q < 8; ++q) acc[q] += ar[q * LK_] * vv;
  }
  if (kh == 1) {
#pragma unroll
    for (int q = 0; q < 8; ++q) p_lds[q][d] = acc[q];
  }
  __syncthreads();
  if (kh == 0) {
    float* __restrict__ ob = out + row0 * D_ + d;
#pragma unroll
    for (int q = 0; q < 8; ++q) ob[q * D_] = acc[q] + p_lds[q][d];
  }
}

extern "C" void kernel_launch(void* const* d_in, const int* in_sizes, int n_in,
                              void* d_out, int out_size, void* d_ws, size_t ws_size,
                              hipStream_t stream) {
  (void)in_sizes; (void)n_in; (void)out_size; (void)ws_size;
  const float* query = (const float*)d_in[0];
  const float* key   = (const float*)d_in[1];
  const float* value = (const float*)d_in[2];
  const int*   mask  = (const int*)d_in[3];
  const float* W1    = (const float*)d_in[4];
  const float* b1    = (const float*)d_in[5];
  const float* W2    = (const float*)d_in[6];
  const float* b2    = (const float*)d_in[7];
  const float* W3    = (const float*)d_in[8];
  const float* b3    = (const float*)d_in[9];

  float* out  = (float*)d_out;                 // (B,LQ,D)   = 262144 floats
  float* attn = out + B_ * LQ_ * D_;           // (B,LQ,LK)  = 524288 floats

  // ws: qp, kp, w2t only (R1/R3-proven layout; nothing else aliases ws)
  float*  qp  = (float*)d_ws;                  // (B*LQ, H1) fp32
  float*  kp  = qp + B_ * LQ_ * H1_;           // (B*LK, H1) fp32
  __bf16* w2t = (__bf16*)(kp + B_ * LK_ * H1_);// (H2, H1) bf16

  prep_kernel<<<320, 512, 0, stream>>>(query, key, W1, b1, W2, qp, kp, w2t);
  dim3 gscore(LK_ / 16, LQ_ / 8, B_);
  score_kernel<<<gscore, 256, 0, stream>>>(qp, kp, w2t, b2, W3, b3, attn);
  smout_kernel<<<dim3(64, B_), 512, 0, stream>>>(attn, mask, value, out);
}

// Round 5
// 152.633 us; speedup vs baseline: 1.0964x; 1.0964x over previous
//
#include <hip/hip_runtime.h>

#define D_  256
#define H1_ 256
#define H2_ 128
#define B_  2
#define LQ_ 512
#define LK_ 512
#define BK  64

typedef float  f32x4  __attribute__((ext_vector_type(4)));
typedef __bf16 bf16x8 __attribute__((ext_vector_type(8)));
typedef __bf16 bf16x4 __attribute__((ext_vector_type(4)));

// ---- prep: qp = query@W1[:D] + b1 ; kp = key@W1[D:] ; w2t = bf16(W2^T) ----
// v2: 4 rows/block -> 512 projection blocks (2 blocks/CU) + 64 w2t blocks.
__global__ __launch_bounds__(512) void prep_kernel(
    const float* __restrict__ query, const float* __restrict__ key,
    const float* __restrict__ W1, const float* __restrict__ b1,
    const float* __restrict__ W2,
    float* __restrict__ qp, float* __restrict__ kp, __bf16* __restrict__ w2t) {
  const int blk = blockIdx.x;
  const int tid = threadIdx.x;
  if (blk >= 512) {
    // 64 blocks x 512 threads = 32768 = H2*H1 elements of W2^T (bf16)
    const int id = (blk - 512) * 512 + tid;
    const int n = id >> 8;
    const int k = id & 255;
    w2t[n * H1_ + k] = (__bf16)W2[k * H2_ + n];
    return;
  }
  __shared__ float in_lds[4][D_];
  __shared__ float part[4][H1_];
  const int row0 = blk * 4;              // rows 0..1023 -> qp, 1024.. -> kp
  const int sel  = row0 >> 10;
  const float* __restrict__ src = sel ? key : query;
  const int base = (row0 & 1023) * D_;
  for (int i = tid; i < 4 * D_; i += 512)
    in_lds[i >> 8][i & 255] = src[base + i];
  __syncthreads();
  const int h  = tid & 255;
  const int kh = tid >> 8;
  float acc[4] = {0.f, 0.f, 0.f, 0.f};
  const float* __restrict__ w = W1 + sel * D_ * H1_ + kh * 128 * H1_ + h;
#pragma unroll 4
  for (int dd = 0; dd < 128; ++dd) {
    const float wv = w[dd * H1_];
    const int d = kh * 128 + dd;
#pragma unroll
    for (int r = 0; r < 4; ++r) acc[r] += in_lds[r][d] * wv;
  }
  if (kh == 1) {
#pragma unroll
    for (int r = 0; r < 4; ++r) part[r][h] = acc[r];
  }
  __syncthreads();
  if (kh == 0) {
    const float bias = sel ? 0.0f : b1[h];
    float* __restrict__ dst = sel ? kp : qp;
#pragma unroll
    for (int r = 0; r < 4; ++r)
      dst[base + r * H1_ + h] = acc[r] + part[r][h] + bias;
  }
}

// ---- score kernel: XOR-swizzled LDS (0 conflicts, R4-verified) +
// launch_bounds(256,2) (no spill, R3-verified). LDS 33.8 KB. ----
__global__ __launch_bounds__(256, 2) void score_kernel(
    const float* __restrict__ qp, const float* __restrict__ kp,
    const __bf16* __restrict__ w2t,
    const float* __restrict__ b2, const float* __restrict__ W3,
    const float* __restrict__ b3, float* __restrict__ scores) {
  __shared__ __align__(16) __bf16 A_lds[128 * BK];   // 16 KB
  __shared__ __align__(16) __bf16 B_lds[128 * BK];   // 16 KB
  __shared__ float  spart[2][128];                   // 1 KB

  const int b  = blockIdx.z;
  const int q0 = blockIdx.y * 8;
  const int k0 = blockIdx.x * 16;
  const int tid  = threadIdx.x;
  const int wave = tid >> 6;
  const int lane = tid & 63;
  const int quad = lane >> 4;
  const int l16  = lane & 15;
  const int wm   = wave >> 1;
  const int wn   = wave & 1;
  const int h8   = l16 & 7;          // row&7 for this lane's fragment rows

  const float* __restrict__ qpb = qp + (b * LQ_ + q0) * H1_;
  const float* __restrict__ kpb = kp + (b * LK_ + k0) * H1_;

  f32x4 acc[4][4];
#pragma unroll
  for (int mt = 0; mt < 4; ++mt)
#pragma unroll
    for (int nt = 0; nt < 4; ++nt)
      acc[mt][nt] = (f32x4){0.f, 0.f, 0.f, 0.f};

  for (int kc = 0; kc < H1_ / BK; ++kc) {
    // --- A tile: A[r][k] = relu(qp[qi][k] + kp[ki][k]), swizzled store ---
#pragma unroll
    for (int i = 0; i < 8; ++i) {
      const int r  = i * 16 + (tid >> 4);
      const int kg = tid & 15;               // b64 piece: k = kg*4..kg*4+3
      const int qi = r >> 4, ki = r & 15;
      const int kcol = kc * BK + kg * 4;
      const float4 qv = *(const float4*)(qpb + qi * H1_ + kcol);
      const float4 kv = *(const float4*)(kpb + ki * H1_ + kcol);
      bf16x4 a;
      a[0] = (__bf16)fmaxf(qv.x + kv.x, 0.f);
      a[1] = (__bf16)fmaxf(qv.y + kv.y, 0.f);
      a[2] = (__bf16)fmaxf(qv.z + kv.z, 0.f);
      a[3] = (__bf16)fmaxf(qv.w + kv.w, 0.f);
      const int sw = (((kg >> 1) ^ (r & 7)) << 3) + ((kg & 1) << 2);
      *(bf16x4*)(&A_lds[r * BK + sw]) = a;
    }
    // --- B tile: 1024 16-B chunks, swizzled ---
#pragma unroll
    for (int i = 0; i < 4; ++i) {
      const int u = i * 256 + tid;
      const int n = u >> 3, c = u & 7;
      *(uint4*)(&B_lds[n * BK + ((c ^ (n & 7)) << 3)]) =
          *(const uint4*)(w2t + n * H1_ + kc * BK + c * 8);
    }
    __syncthreads();
#pragma unroll
    for (int ks = 0; ks < BK / 32; ++ks) {
      const int cbase = ks * 4 + quad;       // chunk index 0..7
      bf16x8 af[4], bfr[4];
#pragma unroll
      for (int mt = 0; mt < 4; ++mt) {
        const int ra = wm * 64 + mt * 16 + l16;
        af[mt] = *(const bf16x8*)(&A_lds[ra * BK + ((cbase ^ h8) << 3)]);
      }
#pragma unroll
      for (int nt = 0; nt < 4; ++nt) {
        const int rb = wn * 64 + nt * 16 + l16;
        bfr[nt] = *(const bf16x8*)(&B_lds[rb * BK + ((cbase ^ h8) << 3)]);
      }
#pragma unroll
      for (int mt = 0; mt < 4; ++mt)
#pragma unroll
        for (int nt = 0; nt < 4; ++nt)
          acc[mt][nt] = __builtin_amdgcn_mfma_f32_16x16x32_bf16(
              af[mt], bfr[nt], acc[mt][nt], 0, 0, 0);
    }
    __syncthreads();
  }

  // --- epilogue: score = sum_n relu(h2 + b2[n]) * W3[n] + b3 ---
  float part[4][4];
#pragma unroll
  for (int mt = 0; mt < 4; ++mt)
#pragma unroll
    for (int rg = 0; rg < 4; ++rg) part[mt][rg] = 0.f;
#pragma unroll
  for (int nt = 0; nt < 4; ++nt) {
    const int col = wn * 64 + nt * 16 + l16;
    const float b2v = b2[col];
    const float w3v = W3[col];
#pragma unroll
    for (int mt = 0; mt < 4; ++mt)
#pragma unroll
      for (int rg = 0; rg < 4; ++rg) {
        float h2 = acc[mt][nt][rg] + b2v;
        h2 = fmaxf(h2, 0.f);
        part[mt][rg] += h2 * w3v;
      }
  }
#pragma unroll
  for (int off = 1; off < 16; off <<= 1)
#pragma unroll
    for (int mt = 0; mt < 4; ++mt)
#pragma unroll
      for (int rg = 0; rg < 4; ++rg)
        part[mt][rg] += __shfl_xor(part[mt][rg], off, 64);
  if (l16 == 0) {
#pragma unroll
    for (int mt = 0; mt < 4; ++mt)
#pragma unroll
      for (int rg = 0; rg < 4; ++rg) {
        const int rl = wm * 64 + mt * 16 + quad * 4 + rg;
        spart[wn][rl] = part[mt][rg];
      }
  }
  __syncthreads();
  if (tid < 128) {
    const float s = spart[0][tid] + spart[1][tid] + b3[0];
    const int qi = tid >> 4, ki = tid & 15;
    scores[(b * LQ_ + q0 + qi) * LK_ + k0 + ki] = s;
  }
}

// ---- softmax over k per (b,q) row, with mask (R3-verified) ----
__global__ void softmax_kernel(float* __restrict__ attn,
                               const int* __restrict__ mask) {
  const int row = blockIdx.x;
  const int tid = threadIdx.x;
  __shared__ float redm[4];
  __shared__ float reds[4];
  float* __restrict__ arow = attn + row * LK_;
  const int* __restrict__ mrow = mask + row * LK_;
  float s0 = arow[tid], s1 = arow[tid + 256];
  if (mrow[tid] == 0)       s0 = -1e9f;
  if (mrow[tid + 256] == 0) s1 = -1e9f;
  float m = fmaxf(s0, s1);
#pragma unroll
  for (int off = 32; off; off >>= 1) m = fmaxf(m, __shfl_xor(m, off, 64));
  if ((tid & 63) == 0) redm[tid >> 6] = m;
  __syncthreads();
  m = fmaxf(fmaxf(redm[0], redm[1]), fmaxf(redm[2], redm[3]));
  const float e0 = __expf(s0 - m), e1 = __expf(s1 - m);
  float sum = e0 + e1;
#pragma unroll
  for (int off = 32; off; off >>= 1) sum += __shfl_xor(sum, off, 64);
  if ((tid & 63) == 0) reds[tid >> 6] = sum;
  __syncthreads();
  sum = reds[0] + reds[1] + reds[2] + reds[3];
  const float inv = 1.f / sum;
  arow[tid]       = e0 * inv;
  arow[tid + 256] = e1 * inv;
}

// ---- out = attn @ value, in-block k-split-4 via LDS (R3-verified) ----
__global__ __launch_bounds__(512) void out_kernel2(
    const float* __restrict__ attn, const float* __restrict__ value,
    float* __restrict__ out) {
  const int ds = blockIdx.x, qg = blockIdx.y, b = blockIdx.z;
  const int tid = threadIdx.x;
  __shared__ float a_lds[8][LK_];       // 16 KB
  __shared__ float p_lds[3][8][128];    // 12 KB
  const float* __restrict__ abase = attn + (b * LQ_ + qg * 8) * LK_;
  for (int i = tid; i < 8 * LK_; i += 512)
    a_lds[i >> 9][i & 511] = abase[i];
  __syncthreads();
  const int dl = tid & 127;
  const int d  = dl + ds * 128;
  const int kh = tid >> 7;              // 0..3
  float acc[8] = {0.f, 0.f, 0.f, 0.f, 0.f, 0.f, 0.f, 0.f};
  const float* __restrict__ vb = value + (b * LK_ + kh * 128) * D_ + d;
#pragma unroll 4
  for (int k = 0; k < 128; ++k) {
    const float v = vb[k * D_];
    const float* __restrict__ ar = &a_lds[0][kh * 128 + k];
#pragma unroll
    for (int q = 0; q < 8; ++q) acc[q] += ar[q * LK_] * v;
  }
  if (kh > 0) {
#pragma unroll
    for (int q = 0; q < 8; ++q) p_lds[kh - 1][q][dl] = acc[q];
  }
  __syncthreads();
  if (kh == 0) {
    float* __restrict__ ob = out + (b * LQ_ + qg * 8) * D_ + d;
#pragma unroll
    for (int q = 0; q < 8; ++q)
      ob[q * D_] = acc[q] + p_lds[0][q][dl] + p_lds[1][q][dl] + p_lds[2][q][dl];
  }
}

extern "C" void kernel_launch(void* const* d_in, const int* in_sizes, int n_in,
                              void* d_out, int out_size, void* d_ws, size_t ws_size,
                              hipStream_t stream) {
  (void)in_sizes; (void)n_in; (void)out_size; (void)ws_size;
  const float* query = (const float*)d_in[0];
  const float* key   = (const float*)d_in[1];
  const float* value = (const float*)d_in[2];
  const int*   mask  = (const int*)d_in[3];
  const float* W1    = (const float*)d_in[4];
  const float* b1    = (const float*)d_in[5];
  const float* W2    = (const float*)d_in[6];
  const float* b2    = (const float*)d_in[7];
  const float* W3    = (const float*)d_in[8];
  const float* b3    = (const float*)d_in[9];

  float* out  = (float*)d_out;                 // (B,LQ,D)   = 262144 floats
  float* attn = out + B_ * LQ_ * D_;           // (B,LQ,LK)  = 524288 floats

  // ws: qp, kp, w2t only (R1/R3-proven layout; nothing else aliases ws)
  float*  qp  = (float*)d_ws;                  // (B*LQ, H1) fp32
  float*  kp  = qp + B_ * LQ_ * H1_;           // (B*LK, H1) fp32
  __bf16* w2t = (__bf16*)(kp + B_ * LK_ * H1_);// (H2, H1) bf16

  prep_kernel<<<576, 512, 0, stream>>>(query, key, W1, b1, W2, qp, kp, w2t);
  dim3 gscore(LK_ / 16, LQ_ / 8, B_);
  score_kernel<<<gscore, 256, 0, stream>>>(qp, kp, w2t, b2, W3, b3, attn);
  softmax_kernel<<<B_ * LQ_, 256, 0, stream>>>(attn, mask);
  out_kernel2<<<dim3(2, 64, B_), 512, 0, stream>>>(attn, value, out);
}

// Round 6
// 147.737 us; speedup vs baseline: 1.1327x; 1.0331x over previous
//
#include <hip/hip_runtime.h>

#define D_  256
#define H1_ 256
#define H2_ 128
#define B_  2
#define LQ_ 512
#define LK_ 512
#define BK  64

typedef float  f32x4  __attribute__((ext_vector_type(4)));
typedef __bf16 bf16x8 __attribute__((ext_vector_type(8)));
typedef __bf16 bf16x4 __attribute__((ext_vector_type(4)));

// ---- prep: qp/kp projections (R5-proven) + W2 in fragment-linear bf16 ----
// w2f layout: frag_id = ((kc*2+ks)*2+wn)*4+nt; element (lane,j) at
// w2f[(frag_id*64+lane)*8+j] = W2[k][n], n = wn*64+nt*16+(lane&15),
// k = kc*64+ks*32+(lane>>4)*8+j. Score waves then load B-frags as fully
// coalesced 1-KB global reads (L2-resident, 64 KB total).
__global__ __launch_bounds__(512) void prep_kernel(
    const float* __restrict__ query, const float* __restrict__ key,
    const float* __restrict__ W1, const float* __restrict__ b1,
    const float* __restrict__ W2,
    float* __restrict__ qp, float* __restrict__ kp, __bf16* __restrict__ w2f) {
  const int blk = blockIdx.x;
  const int tid = threadIdx.x;
  if (blk >= 512) {
    const int id   = (blk - 512) * 512 + tid;   // 0..32767
    const int j    = id & 7;
    const int lane = (id >> 3) & 63;
    const int frag = id >> 9;                   // 0..63
    const int nt = frag & 3;
    const int wn = (frag >> 2) & 1;
    const int ks = (frag >> 3) & 1;
    const int kc = frag >> 4;
    const int n = wn * 64 + nt * 16 + (lane & 15);
    const int k = kc * 64 + ks * 32 + ((lane >> 4) << 3) + j;
    w2f[id] = (__bf16)W2[k * H2_ + n];
    return;
  }
  __shared__ float in_lds[4][D_];
  __shared__ float part[4][H1_];
  const int row0 = blk * 4;              // rows 0..1023 -> qp, 1024.. -> kp
  const int sel  = row0 >> 10;
  const float* __restrict__ src = sel ? key : query;
  const int base = (row0 & 1023) * D_;
  for (int i = tid; i < 4 * D_; i += 512)
    in_lds[i >> 8][i & 255] = src[base + i];
  __syncthreads();
  const int h  = tid & 255;
  const int kh = tid >> 8;
  float acc[4] = {0.f, 0.f, 0.f, 0.f};
  const float* __restrict__ w = W1 + sel * D_ * H1_ + kh * 128 * H1_ + h;
#pragma unroll 4
  for (int dd = 0; dd < 128; ++dd) {
    const float wv = w[dd * H1_];
    const int d = kh * 128 + dd;
#pragma unroll
    for (int r = 0; r < 4; ++r) acc[r] += in_lds[r][d] * wv;
  }
  if (kh == 1) {
#pragma unroll
    for (int r = 0; r < 4; ++r) part[r][h] = acc[r];
  }
  __syncthreads();
  if (kh == 0) {
    const float bias = sel ? 0.0f : b1[h];
    float* __restrict__ dst = sel ? kp : qp;
#pragma unroll
    for (int r = 0; r < 4; ++r)
      dst[base + r * H1_ + h] = acc[r] + part[r][h] + bias;
  }
}

// ---- score v4: A-only LDS (16.5 KB, XOR-swizzled, 0-conflict R4/R5-proven),
// B fragments global->register (coalesced, L2-hit), A-form with qv reuse.
__global__ __launch_bounds__(256, 2) void score_kernel(
    const float* __restrict__ qp, const float* __restrict__ kp,
    const __bf16* __restrict__ w2f,
    const float* __restrict__ b2, const float* __restrict__ W3,
    const float* __restrict__ b3, float* __restrict__ scores) {
  __shared__ __align__(16) __bf16 A_lds[128 * BK];   // 16 KB
  __shared__ float  spart[2][128];                   // 1 KB

  const int b  = blockIdx.z;
  const int q0 = blockIdx.y * 8;
  const int k0 = blockIdx.x * 16;
  const int tid  = threadIdx.x;
  const int wave = tid >> 6;
  const int lane = tid & 63;
  const int quad = lane >> 4;
  const int l16  = lane & 15;
  const int wm   = wave >> 1;
  const int wn   = wave & 1;
  const int h8   = l16 & 7;

  // A-form mapping: fixed (qi, t5, kg) per thread; iterate 8 ki rows.
  const int qi = tid >> 5;           // 0..7
  const int t5 = (tid >> 4) & 1;     // ki-half
  const int kg = tid & 15;           // float4 group in BK

  const float* __restrict__ qpb = qp + (b * LQ_ + q0) * H1_;
  const float* __restrict__ kpb = kp + (b * LK_ + k0) * H1_;

  f32x4 acc[4][4];
#pragma unroll
  for (int mt = 0; mt < 4; ++mt)
#pragma unroll
    for (int nt = 0; nt < 4; ++nt)
      acc[mt][nt] = (f32x4){0.f, 0.f, 0.f, 0.f};

  for (int kc = 0; kc < H1_ / BK; ++kc) {
    // --- B fragments for this kc: 8 coalesced 16-B loads -> registers ---
    bf16x8 bfr[2][4];
#pragma unroll
    for (int ks = 0; ks < 2; ++ks)
#pragma unroll
      for (int nt = 0; nt < 4; ++nt)
        bfr[ks][nt] = *(const bf16x8*)(
            w2f + ((((kc * 2 + ks) * 2 + wn) * 4 + nt) * 64 + lane) * 8);

    // --- A tile: relu(qp[qi]+kp[ki]) bf16, swizzled store, qv reused 8x ---
    const float4 qv = *(const float4*)(qpb + qi * H1_ + kc * BK + kg * 4);
#pragma unroll
    for (int ii = 0; ii < 8; ++ii) {
      const int ki = t5 * 8 + ii;
      const int r  = qi * 16 + ki;
      const float4 kv = *(const float4*)(kpb + ki * H1_ + kc * BK + kg * 4);
      bf16x4 a;
      a[0] = (__bf16)fmaxf(qv.x + kv.x, 0.f);
      a[1] = (__bf16)fmaxf(qv.y + kv.y, 0.f);
      a[2] = (__bf16)fmaxf(qv.z + kv.z, 0.f);
      a[3] = (__bf16)fmaxf(qv.w + kv.w, 0.f);
      const int sw = (((kg >> 1) ^ (r & 7)) << 3) + ((kg & 1) << 2);
      *(bf16x4*)(&A_lds[r * BK + sw]) = a;
    }
    __syncthreads();
#pragma unroll
    for (int ks = 0; ks < 2; ++ks) {
      const int cbase = ks * 4 + quad;
      bf16x8 af[4];
#pragma unroll
      for (int mt = 0; mt < 4; ++mt) {
        const int ra = wm * 64 + mt * 16 + l16;
        af[mt] = *(const bf16x8*)(&A_lds[ra * BK + ((cbase ^ h8) << 3)]);
      }
#pragma unroll
      for (int mt = 0; mt < 4; ++mt)
#pragma unroll
        for (int nt = 0; nt < 4; ++nt)
          acc[mt][nt] = __builtin_amdgcn_mfma_f32_16x16x32_bf16(
              af[mt], bfr[ks][nt], acc[mt][nt], 0, 0, 0);
    }
    __syncthreads();
  }

  // --- epilogue: score = sum_n relu(h2 + b2[n]) * W3[n] + b3 (proven) ---
  float part[4][4];
#pragma unroll
  for (int mt = 0; mt < 4; ++mt)
#pragma unroll
    for (int rg = 0; rg < 4; ++rg) part[mt][rg] = 0.f;
#pragma unroll
  for (int nt = 0; nt < 4; ++nt) {
    const int col = wn * 64 + nt * 16 + l16;
    const float b2v = b2[col];
    const float w3v = W3[col];
#pragma unroll
    for (int mt = 0; mt < 4; ++mt)
#pragma unroll
      for (int rg = 0; rg < 4; ++rg) {
        float h2 = acc[mt][nt][rg] + b2v;
        h2 = fmaxf(h2, 0.f);
        part[mt][rg] += h2 * w3v;
      }
  }
#pragma unroll
  for (int off = 1; off < 16; off <<= 1)
#pragma unroll
    for (int mt = 0; mt < 4; ++mt)
#pragma unroll
      for (int rg = 0; rg < 4; ++rg)
        part[mt][rg] += __shfl_xor(part[mt][rg], off, 64);
  if (l16 == 0) {
#pragma unroll
    for (int mt = 0; mt < 4; ++mt)
#pragma unroll
      for (int rg = 0; rg < 4; ++rg) {
        const int rl = wm * 64 + mt * 16 + quad * 4 + rg;
        spart[wn][rl] = part[mt][rg];
      }
  }
  __syncthreads();
  if (tid < 128) {
    const float s = spart[0][tid] + spart[1][tid] + b3[0];
    const int qi2 = tid >> 4, ki2 = tid & 15;
    scores[(b * LQ_ + q0 + qi2) * LK_ + k0 + ki2] = s;
  }
}

// ---- fused softmax + out. Scores come from ws scratch (read-only here), so
// the two ds-blocks sharing rows never race: probs written to attn by ds==0
// only; phase 2 = R5 out_kernel2 (proven), reading probs from LDS.
__global__ __launch_bounds__(512) void smout_kernel(
    const float* __restrict__ sc, float* __restrict__ attn,
    const int* __restrict__ mask, const float* __restrict__ value,
    float* __restrict__ out) {
  const int ds = blockIdx.x, qg = blockIdx.y, b = blockIdx.z;
  const int tid = threadIdx.x;
  __shared__ float a_lds[8][LK_];       // 16 KB probs
  __shared__ float p_lds[3][8][128];    // 12 KB partials
  const int row0 = b * LQ_ + qg * 8;
  const int w = tid >> 6, lane = tid & 63;
  // phase 1: wave w softmaxes row w (R4-proven reduce)
  {
    const float* __restrict__ srow = sc + (row0 + w) * LK_;
    const int*  __restrict__ mrow = mask + (row0 + w) * LK_;
    float v[8];
#pragma unroll
    for (int j = 0; j < 8; ++j) {
      float s = srow[lane + j * 64];
      if (mrow[lane + j * 64] == 0) s = -1e9f;
      v[j] = s;
    }
    float m = v[0];
#pragma unroll
    for (int j = 1; j < 8; ++j) m = fmaxf(m, v[j]);
#pragma unroll
    for (int off = 32; off; off >>= 1) m = fmaxf(m, __shfl_xor(m, off, 64));
    float sum = 0.f;
#pragma unroll
    for (int j = 0; j < 8; ++j) { v[j] = __expf(v[j] - m); sum += v[j]; }
#pragma unroll
    for (int off = 32; off; off >>= 1) sum += __shfl_xor(sum, off, 64);
    const float inv = 1.f / sum;
    float* __restrict__ arow = attn + (row0 + w) * LK_;
#pragma unroll
    for (int j = 0; j < 8; ++j) {
      const float p = v[j] * inv;
      a_lds[w][lane + j * 64] = p;
      if (ds == 0) arow[lane + j * 64] = p;
    }
  }
  __syncthreads();
  // phase 2: out = probs @ value (kh-split-4, R5-proven)
  const int dl = tid & 127;
  const int d  = dl + ds * 128;
  const int kh = tid >> 7;
  float acc[8] = {0.f, 0.f, 0.f, 0.f, 0.f, 0.f, 0.f, 0.f};
  const float* __restrict__ vb = value + (b * LK_ + kh * 128) * D_ + d;
#pragma unroll 4
  for (int k = 0; k < 128; ++k) {
    const float v = vb[k * D_];
    const float* __restrict__ ar = &a_lds[0][kh * 128 + k];
#pragma unroll
    for (int q = 0; q < 8; ++q) acc[q] += ar[q * LK_] * v;
  }
  if (kh > 0) {
#pragma unroll
    for (int q = 0; q < 8; ++q) p_lds[kh - 1][q][dl] = acc[q];
  }
  __syncthreads();
  if (kh == 0) {
    float* __restrict__ ob = out + row0 * D_ + d;
#pragma unroll
    for (int q = 0; q < 8; ++q)
      ob[q * D_] = acc[q] + p_lds[0][q][dl] + p_lds[1][q][dl] + p_lds[2][q][dl];
  }
}

extern "C" void kernel_launch(void* const* d_in, const int* in_sizes, int n_in,
                              void* d_out, int out_size, void* d_ws, size_t ws_size,
                              hipStream_t stream) {
  (void)in_sizes; (void)n_in; (void)out_size; (void)ws_size;
  const float* query = (const float*)d_in[0];
  const float* key   = (const float*)d_in[1];
  const float* value = (const float*)d_in[2];
  const int*   mask  = (const int*)d_in[3];
  const float* W1    = (const float*)d_in[4];
  const float* b1    = (const float*)d_in[5];
  const float* W2    = (const float*)d_in[6];
  const float* b2    = (const float*)d_in[7];
  const float* W3    = (const float*)d_in[8];
  const float* b3    = (const float*)d_in[9];

  float* out  = (float*)d_out;                 // (B,LQ,D)   = 262144 floats
  float* attn = out + B_ * LQ_ * D_;           // (B,LQ,LK)  = 524288 floats

  // ws: qp (2MB) + kp (2MB) + w2f (64KB) + sc scratch scores (2MB)
  float*  qp  = (float*)d_ws;                  // (B*LQ, H1) fp32
  float*  kp  = qp + B_ * LQ_ * H1_;           // (B*LK, H1) fp32
  __bf16* w2f = (__bf16*)(kp + B_ * LK_ * H1_);// frag-linear W2, 32768 bf16
  float*  sc  = (float*)(w2f + H2_ * H1_);     // (B,LQ,LK) raw scores

  prep_kernel<<<576, 512, 0, stream>>>(query, key, W1, b1, W2, qp, kp, w2f);
  dim3 gscore(LK_ / 16, LQ_ / 8, B_);
  score_kernel<<<gscore, 256, 0, stream>>>(qp, kp, w2f, b2, W3, b3, sc);
  smout_kernel<<<dim3(2, 64, B_), 512, 0, stream>>>(sc, attn, mask, value, out);
}